// Round 7
// baseline (2091.708 us; speedup 1.0000x reference)
//
#include <hip/hip_runtime.h>

#define NL   8
#define DIM  2048
#define NH   8
#define NKV  2
#define HD   256
#define KVL  4096
#define FFI  8192
#define PLD  256
#define POS  2047
#define NCH  256   // attention chunks (CP positions each)
#define CP   8
#define NBLK 256
#define NTHR 1024

struct MegaP {
  const float *hidden, *plc, *cos_s, *sin_s, *cos_f, *sin_f;
  const float *K_in, *V_in;
  const float *w_q, *w_k, *w_v, *w_o;
  const float *g_in, *g_q, *g_k, *g_pa, *g_pf, *g_ff;
  const float *w_gate, *w_up, *w_down, *w_plg, *w_plp, *g_pl, *lsc;
  float *out, *outK, *outV;
  float *hA, *hB, *hC, *qkvb, *y, *t, *mv, *u;
  float *pm, *pl, *po, *po2, *Mq, *Lq;
  unsigned *cnt;
};

typedef float vfloat4 __attribute__((ext_vector_type(4)));

__device__ __forceinline__ float dot4(float4 a, float4 b){
  return a.x*b.x + a.y*b.y + a.z*b.z + a.w*b.w;
}

__device__ __forceinline__ float4 ntld4(const float4* p){
  vfloat4 v = __builtin_nontemporal_load((const vfloat4*)p);
  float4 r; r.x=v.x; r.y=v.y; r.z=v.z; r.w=v.w;
  return r;
}
__device__ __forceinline__ void ntst4(float4* p, float4 v){
  vfloat4 t; t.x=v.x; t.y=v.y; t.z=v.z; t.w=v.w;
  __builtin_nontemporal_store(t, (vfloat4*)p);
}

__device__ __forceinline__ float waveAllSum(float v){
#pragma unroll
  for(int o=1;o<64;o<<=1) v += __shfl_xor(v,o,64);
  return v;
}

__device__ __forceinline__ float waveAllMax(float v){
#pragma unroll
  for(int o=1;o<64;o<<=1) v = fmaxf(v, __shfl_xor(v,o,64));
  return v;
}

__device__ __forceinline__ float blockSum1024(float v, float* red){
  int lane = threadIdx.x & 63, w = threadIdx.x >> 6;
  v = waveAllSum(v);
  __syncthreads();
  if(lane==0) red[w] = v;
  __syncthreads();
  float s = 0.f;
#pragma unroll
  for(int i=0;i<16;i++) s += red[i];
  return s;
}

__device__ __forceinline__ float gelu_tanh(float v){
  return 0.5f*v*(1.0f + tanhf(0.7978845608028654f*(v + 0.044715f*v*v*v)));
}

// wave-level rms(+gain)(+rope) of a 256-float vector
__device__ __forceinline__ float4 normRope(const float* __restrict__ raw, int lane,
    const float* __restrict__ gain, const float* __restrict__ cosT,
    const float* __restrict__ sinT, bool doRope){
  float4 v4 = ((const float4*)raw)[lane];
  float ss = waveAllSum(dot4(v4,v4));
  float sc = rsqrtf(ss*(1.f/HD) + 1e-6f);
  float4 n;
  if(gain){
    float4 g4 = ((const float4*)gain)[lane];
    n.x=v4.x*sc*g4.x; n.y=v4.y*sc*g4.y; n.z=v4.z*sc*g4.z; n.w=v4.w*sc*g4.w;
  } else {
    n.x=v4.x*sc; n.y=v4.y*sc; n.z=v4.z*sc; n.w=v4.w*sc;
  }
  if(!doRope) return n;
  float4 np;
  np.x=__shfl_xor(n.x,32,64); np.y=__shfl_xor(n.y,32,64);
  np.z=__shfl_xor(n.z,32,64); np.w=__shfl_xor(n.w,32,64);
  float4 c4 = ((const float4*)cosT)[lane];
  float4 s4 = ((const float4*)sinT)[lane];
  float sg = (lane < 32) ? -1.f : 1.f;
  float4 o;
  o.x = n.x*c4.x + sg*np.x*s4.x;
  o.y = n.y*c4.y + sg*np.y*s4.y;
  o.z = n.z*c4.z + sg*np.z*s4.z;
  o.w = n.w*c4.w + sg*np.w*s4.w;
  return o;
}

// single-counter grid barrier: 1 fetch_add per block + single-line spin
__device__ __forceinline__ void gridBarrier(unsigned* cnt, unsigned g){
  __syncthreads();
  if(threadIdx.x == 0){
    __builtin_amdgcn_fence(__ATOMIC_RELEASE, "agent");
    unsigned* c = cnt + (size_t)g*16;
    __hip_atomic_fetch_add(c, 1u, __ATOMIC_RELAXED, __HIP_MEMORY_SCOPE_AGENT);
    while(__hip_atomic_load(c, __ATOMIC_RELAXED, __HIP_MEMORY_SCOPE_AGENT) < NBLK)
      __builtin_amdgcn_s_sleep(2);
    __builtin_amdgcn_fence(__ATOMIC_ACQUIRE, "agent");
  }
  __syncthreads();
}

__global__ __launch_bounds__(NTHR, 4) void mega_k(MegaP p){
  __shared__ float xs[FFI];   // 32 KB staging
  __shared__ float red[16];
  float4* xs4 = (float4*)xs;

  const int tid  = threadIdx.x;
  const int bid  = blockIdx.x;
  const int lane = tid & 63;
  const int wv   = tid >> 6;
  const int gw   = bid*16 + wv;      // 0..4095
  unsigned g = 0;

  for(int l=0; l<NL; l++){
    const float* Wq  = p.w_q    + (size_t)l*NH*HD*DIM;
    const float* Wk  = p.w_k    + (size_t)l*NKV*HD*DIM;
    const float* Wv  = p.w_v    + (size_t)l*NKV*HD*DIM;
    const float* Wo  = p.w_o    + (size_t)l*DIM*NH*HD;
    const float* Wg  = p.w_gate + (size_t)l*FFI*DIM;
    const float* Wu  = p.w_up   + (size_t)l*FFI*DIM;
    const float* Wd  = p.w_down + (size_t)l*DIM*FFI;
    const float* Wpg = p.w_plg  + (size_t)l*PLD*DIM;
    const float* Wpp = p.w_plp  + (size_t)l*DIM*PLD;
    const float* cosT = (l==4) ? p.cos_f : p.cos_s;
    const float* sinT = (l==4) ? p.sin_f : p.sin_s;
    const float* gq = p.g_q + (size_t)l*HD;
    const float* gk = p.g_k + (size_t)l*HD;
    float* Kl = p.outK + (size_t)l*NKV*KVL*HD;
    float* Vl = p.outV + (size_t)l*NKV*KVL*HD;
    const float* Ki = p.K_in + (size_t)l*NKV*KVL*HD;
    const float* Vi = p.V_in + (size_t)l*NKV*KVL*HD;

    // ======== Phase A: prologue + qkv GEMV (3072 waves) + copy K rows 0..4095 ========
    {
      float hv0, hv1;
      if(l==0){
        hv0 = p.hidden[tid]; hv1 = p.hidden[tid+1024];
      } else {
        const float* gpl = p.g_pl + (size_t)(l-1)*DIM;
        float ls = p.lsc[l-1];
        float u0 = p.u[tid], u1 = p.u[tid+1024];
        float ss = blockSum1024(u0*u0 + u1*u1, red);
        float r1 = rsqrtf(ss*(1.f/DIM) + 1e-6f);
        hv0 = (p.hC[tid]      + u0*r1*gpl[tid])*ls;
        hv1 = (p.hC[tid+1024] + u1*r1*gpl[tid+1024])*ls;
      }
      float ss2 = blockSum1024(hv0*hv0 + hv1*hv1, red);
      float r2 = rsqrtf(ss2*(1.f/DIM) + 1e-6f);
      const float* gin = p.g_in + (size_t)l*DIM;
      xs[tid]      = hv0*r2*gin[tid];
      xs[tid+1024] = hv1*r2*gin[tid+1024];
      if(bid==0){ p.hA[tid] = hv0; p.hA[tid+1024] = hv1; }
      __syncthreads();

      if((gw&3) != 3){
        int r = (gw>>2)*3 + (gw&3);      // 0..3071
        const float* W; int row;
        if(r < 2048){ W = Wq; row = r; }
        else if(r < 2560){ W = Wk; row = r - 2048; }
        else { W = Wv; row = r - 2560; }
        const float4* Wr = (const float4*)(W + (size_t)row*DIM);
        float acc = 0.f;
#pragma unroll
        for(int i=0;i<8;i++) acc += dot4(ntld4(Wr + i*64+lane), xs4[i*64+lane]);
        acc = waveAllSum(acc);
        if(lane==0) p.qkvb[r] = acc;
      } else {
        int cw = gw>>2;                  // 0..1023 -> K rows 0..4095 (pre-POS-write)
        const float4* s = (const float4*)Ki;
        float4* d = (float4*)Kl;
        float4 v0 = ntld4(s + (size_t)(cw*4+0)*64+lane);
        float4 v1 = ntld4(s + (size_t)(cw*4+1)*64+lane);
        float4 v2 = ntld4(s + (size_t)(cw*4+2)*64+lane);
        float4 v3 = ntld4(s + (size_t)(cw*4+3)*64+lane);
        ntst4(d + (size_t)(cw*4+0)*64+lane, v0);
        ntst4(d + (size_t)(cw*4+1)*64+lane, v1);
        ntst4(d + (size_t)(cw*4+2)*64+lane, v2);
        ntst4(d + (size_t)(cw*4+3)*64+lane, v3);
      }
    }
    gridBarrier(p.cnt, g++);

    // ======== Phase B: attention partials (512 waves) + POS writers + copy filler ========
    if((gw&7) == 0){
      int pair = gw>>3;                  // 0..511
      int kv = pair & 1, c = pair >> 1;  // c: 0..255
      float4 q4[4];
#pragma unroll
      for(int hh=0;hh<4;hh++)
        q4[hh] = normRope(p.qkvb + (kv*4+hh)*HD, lane, gq, cosT, sinT, true);
      bool last = (c == NCH-1);
      float4 kf4 = {0,0,0,0}, vf4 = {0,0,0,0};
      if(last){
        kf4 = normRope(p.qkvb + 2048 + kv*HD, lane, gk, cosT, sinT, true);
        vf4 = normRope(p.qkvb + 2560 + kv*HD, lane, nullptr, cosT, sinT, false);
      }
      float sc[4] = {-1e30f,-1e30f,-1e30f,-1e30f};
      const float4* Kp = (const float4*)(Ki + (size_t)kv*KVL*HD);
#pragma unroll
      for(int j=0;j<CP;j++){
        int pp = c*CP + j;
        float4 k4 = (last && j==CP-1) ? kf4 : Kp[(size_t)pp*64 + lane];
#pragma unroll
        for(int hh=0;hh<4;hh++){
          float d = waveAllSum(dot4(k4, q4[hh]));
          if(lane==j) sc[hh] = d;
        }
      }
      float e[4];
#pragma unroll
      for(int hh=0;hh<4;hh++){
        float mm = sc[hh];
#pragma unroll
        for(int o=1;o<8;o<<=1) mm = fmaxf(mm, __shfl_xor(mm,o,64));
        e[hh] = __expf(sc[hh]-mm);
        float ll = e[hh];
#pragma unroll
        for(int o=1;o<8;o<<=1) ll += __shfl_xor(ll,o,64);
        if(lane==0){
          int hg = kv*4 + hh;
          p.pm[hg*NCH + c] = mm;
          p.pl[hg*NCH + c] = ll;
        }
      }
      float4 acc4[4] = {{0,0,0,0},{0,0,0,0},{0,0,0,0},{0,0,0,0}};
      const float4* Vp = (const float4*)(Vi + (size_t)kv*KVL*HD);
#pragma unroll
      for(int j=0;j<CP;j++){
        int pp = c*CP + j;
        float4 v4 = (last && j==CP-1) ? vf4 : Vp[(size_t)pp*64 + lane];
#pragma unroll
        for(int hh=0;hh<4;hh++){
          float w = __shfl(e[hh], j, 64);
          acc4[hh].x += w*v4.x; acc4[hh].y += w*v4.y;
          acc4[hh].z += w*v4.z; acc4[hh].w += w*v4.w;
        }
      }
#pragma unroll
      for(int hh=0;hh<4;hh++){
        int hg = kv*4 + hh;
        ((float4*)p.po)[(size_t)(hg*NCH + c)*64 + lane] = acc4[hh];
      }
    } else {
      if((gw&7)==1 && (gw>>3) < 4){      // POS-row writer (also copies below)
        int w = gw>>3; int kvv = w>>1, isV = w&1;
        float4 o = isV ? normRope(p.qkvb + 2560 + kvv*HD, lane, nullptr, cosT, sinT, false)
                       : normRope(p.qkvb + 2048 + kvv*HD, lane, gk, cosT, sinT, true);
        float* dst = (isV ? Vl : Kl) + ((size_t)kvv*KVL + POS)*HD;
        ((float4*)dst)[lane] = o;
      }
      int k = (gw>>3)*7 + (gw&7) - 1;    // 0..3583
#pragma unroll
      for(int j=0;j<4;j++){
        int idx = k*4 + j;
        if(idx < 12285){
          int row = 4096 + idx;          // skip POS rows written this phase
          if(row >= 6143)  row++;
          if(row >= 10239) row++;
          if(row >= 14335) row++;
          const float4* s; float4* d; int rr;
          if(row < 8192){ rr = row;       s = (const float4*)Ki; d = (float4*)Kl; }
          else          { rr = row-8192;  s = (const float4*)Vi; d = (float4*)Vl; }
          ntst4(d + (size_t)rr*64+lane, ntld4(s + (size_t)rr*64+lane));
        }
      }
    }
    gridBarrier(p.cnt, g++);

    // ======== Phase B2: quarter-combine (32 waves, spread) ========
    if((gw&127) == 0){
      int q32 = gw>>7, h = q32>>2, qq = q32&3;
      float pmv = p.pm[h*NCH + qq*64 + lane];
      float plv = p.pl[h*NCH + qq*64 + lane];
      float Mq = waveAllMax(pmv);
      float e = __expf(pmv - Mq);
      float Lq = waveAllSum(plv * e);
      float4 acc = {0,0,0,0};
      const float4* pp = (const float4*)p.po + (size_t)(h*NCH + qq*64)*64;
#pragma unroll 8
      for(int c2=0;c2<64;c2++){
        float w = __shfl(e, c2, 64);
        float4 v = pp[c2*64 + lane];
        acc.x += w*v.x; acc.y += w*v.y; acc.z += w*v.z; acc.w += w*v.w;
      }
      ((float4*)p.po2)[q32*64 + lane] = acc;
      if(lane==0){ p.Mq[q32] = Mq; p.Lq[q32] = Lq; }
    }
    gridBarrier(p.cnt, g++);

    // ======== Phase C: final combine (waves 0..7) + wo GEMV ========
    {
      if(wv < 8){
        int h = wv;
        float m0=p.Mq[h*4+0], m1=p.Mq[h*4+1], m2=p.Mq[h*4+2], m3=p.Mq[h*4+3];
        float M = fmaxf(fmaxf(m0,m1), fmaxf(m2,m3));
        float s0=__expf(m0-M), s1=__expf(m1-M), s2=__expf(m2-M), s3=__expf(m3-M);
        float L = s0*p.Lq[h*4+0] + s1*p.Lq[h*4+1] + s2*p.Lq[h*4+2] + s3*p.Lq[h*4+3];
        const float4* q2 = (const float4*)p.po2;
        float4 a0 = q2[(h*4+0)*64+lane], a1 = q2[(h*4+1)*64+lane];
        float4 a2 = q2[(h*4+2)*64+lane], a3 = q2[(h*4+3)*64+lane];
        float inv = 1.f/L;
        float4 ao;
        ao.x = (s0*a0.x + s1*a1.x + s2*a2.x + s3*a3.x)*inv;
        ao.y = (s0*a0.y + s1*a1.y + s2*a2.y + s3*a3.y)*inv;
        ao.z = (s0*a0.z + s1*a1.z + s2*a2.z + s3*a3.z)*inv;
        ao.w = (s0*a0.w + s1*a1.w + s2*a2.w + s3*a3.w)*inv;
        xs4[h*64 + lane] = ao;
      }
      __syncthreads();
      if((gw&1) == 0){
        int r = gw>>1;
        const float4* Wr = (const float4*)(Wo + (size_t)r*DIM);
        float acc = 0.f;
#pragma unroll
        for(int i=0;i<8;i++) acc += dot4(ntld4(Wr + i*64+lane), xs4[i*64+lane]);
        acc = waveAllSum(acc);
        if(lane==0) p.y[r] = acc;
      }
    }
    gridBarrier(p.cnt, g++);

    // ======== Phase D: post_attn prologue + gate/up GEMV (2 j per wave) ========
    {
      float y0 = p.y[tid], y1 = p.y[tid+1024];
      float ss1 = blockSum1024(y0*y0 + y1*y1, red);
      float r1 = rsqrtf(ss1*(1.f/DIM) + 1e-6f);
      const float* gpa = p.g_pa + (size_t)l*DIM;
      const float* gpf = p.g_pf + (size_t)l*DIM;
      float h0 = p.hA[tid]      + y0*r1*gpa[tid];
      float h1 = p.hA[tid+1024] + y1*r1*gpa[tid+1024];
      float ss2 = blockSum1024(h0*h0 + h1*h1, red);
      float r2 = rsqrtf(ss2*(1.f/DIM) + 1e-6f);
      xs[tid]      = h0*r2*gpf[tid];
      xs[tid+1024] = h1*r2*gpf[tid+1024];
      if(bid==0){ p.hB[tid] = h0; p.hB[tid+1024] = h1; }
      __syncthreads();
      int j0 = gw*2, j1 = gw*2+1;
      const float4* G0 = (const float4*)(Wg + (size_t)j0*DIM);
      const float4* G1 = (const float4*)(Wg + (size_t)j1*DIM);
      const float4* U0 = (const float4*)(Wu + (size_t)j0*DIM);
      const float4* U1 = (const float4*)(Wu + (size_t)j1*DIM);
      float a00=0.f, a01=0.f, a10=0.f, a11=0.f;
#pragma unroll
      for(int i=0;i<8;i++){
        float4 bv = xs4[i*64+lane];
        a00 += dot4(ntld4(G0 + i*64+lane), bv);
        a10 += dot4(ntld4(G1 + i*64+lane), bv);
        a01 += dot4(ntld4(U0 + i*64+lane), bv);
        a11 += dot4(ntld4(U1 + i*64+lane), bv);
      }
      a00 = waveAllSum(a00); a01 = waveAllSum(a01);
      a10 = waveAllSum(a10); a11 = waveAllSum(a11);
      if(lane==0){
        p.t[j0] = gelu_tanh(a00)*a01;
        p.t[j1] = gelu_tanh(a10)*a11;
      }
    }
    gridBarrier(p.cnt, g++);

    // ======== Phase E: down GEMV ========
    {
      xs4[tid]      = ((const float4*)p.t)[tid];
      xs4[tid+1024] = ((const float4*)p.t)[tid+1024];
      __syncthreads();
      if((gw&1) == 0){
        int r = gw>>1;
        const float4* Wr = (const float4*)(Wd + (size_t)r*FFI);
        float acc0 = 0.f, acc1 = 0.f;
#pragma unroll
        for(int i=0;i<32;i+=2){
          acc0 += dot4(ntld4(Wr + i*64+lane),     xs4[i*64+lane]);
          acc1 += dot4(ntld4(Wr + (i+1)*64+lane), xs4[(i+1)*64+lane]);
        }
        float acc = waveAllSum(acc0+acc1);
        if(lane==0) p.mv[r] = acc;
      }
    }
    gridBarrier(p.cnt, g++);

    // ======== Phase FG: post_ff prologue + redundant plg (block-local) + plp ========
    {
      float m0 = p.mv[tid], m1 = p.mv[tid+1024];
      float ss1 = blockSum1024(m0*m0 + m1*m1, red);
      float r1 = rsqrtf(ss1*(1.f/DIM) + 1e-6f);
      const float* gff = p.g_ff + (size_t)l*DIM;
      float hc0 = p.hB[tid]      + m0*r1*gff[tid];
      float hc1 = p.hB[tid+1024] + m1*r1*gff[tid+1024];
      xs[tid] = hc0; xs[tid+1024] = hc1;
      if(bid==0){ p.hC[tid] = hc0; p.hC[tid+1024] = hc1; }
      __syncthreads();
      // plg: every block computes all 256 rows (w_plg L2-cached per XCD)
      float* gb_s = xs + 2048;
#pragma unroll
      for(int rr=0;rr<16;rr++){
        int r = wv*16 + rr;
        const float4* Wr = (const float4*)(Wpg + (size_t)r*DIM);
        float acc = 0.f;
#pragma unroll
        for(int i=0;i<8;i++) acc += dot4(Wr[i*64+lane], xs4[i*64+lane]);
        acc = waveAllSum(acc);
        if(lane==0) gb_s[r] = gelu_tanh(acc)*p.plc[l*PLD + r];
      }
      __syncthreads();
      // plp: waves 0..7 -> u rows bid*8+wv
      if(wv < 8){
        int r = bid*8 + wv;
        const float4* Wr = (const float4*)(Wpp + (size_t)r*PLD);
        float acc = dot4(ntld4(Wr + lane), ((const float4*)gb_s)[lane]);
        acc = waveAllSum(acc);
        if(lane==0) p.u[r] = acc;
      }
    }
    gridBarrier(p.cnt, g++);
  }

  // ======== Epilogue: out = (hC + rms(u)*g_pl[7])*ls[7] ========
  if(bid == 0){
    float u0 = p.u[tid], u1 = p.u[tid+1024];
    float ss = blockSum1024(u0*u0 + u1*u1, red);
    float r1 = rsqrtf(ss*(1.f/DIM) + 1e-6f);
    float ls = p.lsc[NL-1];
    const float* gpl = p.g_pl + (size_t)(NL-1)*DIM;
    p.out[tid]      = (p.hC[tid]      + u0*r1*gpl[tid])*ls;
    p.out[tid+1024] = (p.hC[tid+1024] + u1*r1*gpl[tid+1024])*ls;
  }
}

extern "C" void kernel_launch(void* const* d_in, const int* in_sizes, int n_in,
                              void* d_out, int out_size, void* d_ws, size_t ws_size,
                              hipStream_t stream){
  MegaP p;
  p.hidden = (const float*)d_in[0];
  p.plc    = (const float*)d_in[3];
  p.cos_s  = (const float*)d_in[4];
  p.sin_s  = (const float*)d_in[5];
  p.cos_f  = (const float*)d_in[6];
  p.sin_f  = (const float*)d_in[7];
  p.K_in   = (const float*)d_in[8];
  p.V_in   = (const float*)d_in[9];
  p.w_q    = (const float*)d_in[10];
  p.w_k    = (const float*)d_in[11];
  p.w_v    = (const float*)d_in[12];
  p.w_o    = (const float*)d_in[13];
  p.g_in   = (const float*)d_in[14];
  p.g_q    = (const float*)d_in[15];
  p.g_k    = (const float*)d_in[16];
  p.g_pa   = (const float*)d_in[17];
  p.g_pf   = (const float*)d_in[18];
  p.g_ff   = (const float*)d_in[19];
  p.w_gate = (const float*)d_in[20];
  p.w_up   = (const float*)d_in[21];
  p.w_down = (const float*)d_in[22];
  p.w_plg  = (const float*)d_in[23];
  p.w_plp  = (const float*)d_in[24];
  p.g_pl   = (const float*)d_in[25];
  p.lsc    = (const float*)d_in[26];

  float* out = (float*)d_out;
  p.out  = out;
  p.outK = out + DIM;
  p.outV = p.outK + (size_t)NL*NKV*KVL*HD;

  p.cnt = (unsigned*)d_ws;            // 64 generations x 16 uints = 4 KB

  float* fws = (float*)d_ws + 1024;
  p.hA   = fws;
  p.hB   = fws + 2048;
  p.hC   = fws + 4096;
  p.qkvb = fws + 6144;    // 3072
  p.y    = fws + 9216;    // 2048
  p.t    = fws + 11264;   // 8192
  p.mv   = fws + 19456;   // 2048
  p.u    = fws + 21760;   // 2048
  p.pm   = fws + 23808;   // 2048
  p.pl   = fws + 25856;   // 2048
  p.po   = fws + 27904;   // 8*256*256 = 524288
  p.po2  = fws + 552192;  // 32*256 = 8192
  p.Mq   = fws + 560384;  // 32
  p.Lq   = fws + 560416;  // 32

  (void)hipMemsetAsync(d_ws, 0, 4096, stream);
  mega_k<<<NBLK, NTHR, 0, stream>>>(p);
}

// Round 8
// 809.222 us; speedup vs baseline: 2.5848x; 2.5848x over previous
//
#include <hip/hip_runtime.h>

#define NL   8
#define DIM  2048
#define NH   8
#define NKV  2
#define HD   256
#define KVL  4096
#define FFI  8192
#define PLD  256
#define POS  2047
#define NCH  128   // attention chunks
#define CP   16    // positions per chunk

__device__ __forceinline__ float dot4(float4 a, float4 b){
  return a.x*b.x + a.y*b.y + a.z*b.z + a.w*b.w;
}

__device__ __forceinline__ float waveAllSum(float v){
#pragma unroll
  for(int o=1;o<64;o<<=1) v += __shfl_xor(v,o,64);
  return v;
}

__device__ __forceinline__ float blockSum256(float v, float* red){
  int lane = threadIdx.x & 63, w = threadIdx.x >> 6;
  v = waveAllSum(v);
  __syncthreads();
  if(lane==0) red[w] = v;
  __syncthreads();
  return red[0]+red[1]+red[2]+red[3];
}

__device__ __forceinline__ float gelu_tanh(float v){
  return 0.5f*v*(1.0f + tanhf(0.7978845608028654f*(v + 0.044715f*v*v*v)));
}

// wave-level rms(+gain)(+rope) of a 256-float vector
__device__ __forceinline__ float4 normRope(const float* __restrict__ raw, int lane,
    const float* __restrict__ gain, const float* __restrict__ cosT,
    const float* __restrict__ sinT, bool doRope){
  float4 v4 = ((const float4*)raw)[lane];
  float ss = waveAllSum(dot4(v4,v4));
  float sc = rsqrtf(ss*(1.f/HD) + 1e-6f);
  float4 n;
  if(gain){
    float4 g4 = ((const float4*)gain)[lane];
    n.x=v4.x*sc*g4.x; n.y=v4.y*sc*g4.y; n.z=v4.z*sc*g4.z; n.w=v4.w*sc*g4.w;
  } else {
    n.x=v4.x*sc; n.y=v4.y*sc; n.z=v4.z*sc; n.w=v4.w*sc;
  }
  if(!doRope) return n;
  float4 np;
  np.x=__shfl_xor(n.x,32,64); np.y=__shfl_xor(n.y,32,64);
  np.z=__shfl_xor(n.z,32,64); np.w=__shfl_xor(n.w,32,64);
  float4 c4 = ((const float4*)cosT)[lane];
  float4 s4 = ((const float4*)sinT)[lane];
  float sg = (lane < 32) ? -1.f : 1.f;
  float4 o;
  o.x = n.x*c4.x + sg*np.x*s4.x;
  o.y = n.y*c4.y + sg*np.y*s4.y;
  o.z = n.z*c4.z + sg*np.z*s4.z;
  o.w = n.w*c4.w + sg*np.w*s4.w;
  return o;
}

// ---- qkv GEMV with fused post_pl (prev layer) / initial prologue ----
__global__ __launch_bounds__(256) void qkv_k(
    const float* __restrict__ Wq, const float* __restrict__ Wk,
    const float* __restrict__ Wv,
    const float* __restrict__ hC, const float* __restrict__ u,
    const float* __restrict__ g_pl, const float* __restrict__ lsc,
    const float* __restrict__ g_in, const float* __restrict__ hidden,
    float* __restrict__ hA, float* __restrict__ qkv){
  __shared__ float xs[DIM];
  __shared__ float red[4];
  int tid = threadIdx.x;
  float hv[8];
  if(hidden){
#pragma unroll
    for(int i=0;i<8;i++) hv[i] = hidden[tid + i*256];
  } else {
    float uv[8]; float ss1 = 0.f;
#pragma unroll
    for(int i=0;i<8;i++){ uv[i] = u[tid + i*256]; ss1 += uv[i]*uv[i]; }
    ss1 = blockSum256(ss1, red);
    float r1 = rsqrtf(ss1*(1.f/DIM) + 1e-6f);
    float ls = lsc[0];
#pragma unroll
    for(int i=0;i<8;i++){
      int idx = tid + i*256;
      hv[i] = (hC[idx] + uv[i]*r1*g_pl[idx])*ls;
    }
  }
  float ss2 = 0.f;
#pragma unroll
  for(int i=0;i<8;i++) ss2 += hv[i]*hv[i];
  ss2 = blockSum256(ss2, red);
  float r2 = rsqrtf(ss2*(1.f/DIM) + 1e-6f);
#pragma unroll
  for(int i=0;i<8;i++){
    int idx = tid + i*256;
    xs[idx] = hv[i]*r2*g_in[idx];
    if(blockIdx.x==0) hA[idx] = hv[i];
  }
  __syncthreads();
  int lane = tid & 63, wv = tid >> 6;
  int r = blockIdx.x*4 + wv;
  const float* W; int row;
  if(r < 2048){ W = Wq; row = r; }
  else if(r < 2560){ W = Wk; row = r - 2048; }
  else { W = Wv; row = r - 2560; }
  const float4* Wr = (const float4*)(W + (size_t)row*DIM);
  const float4* xs4 = (const float4*)xs;
  float4 w8[8];
#pragma unroll
  for(int i=0;i<8;i++) w8[i] = Wr[i*64+lane];
  float acc = 0.f;
#pragma unroll
  for(int i=0;i<8;i++) acc += dot4(w8[i], xs4[i*64+lane]);
  acc = waveAllSum(acc);
  if(lane==0) qkv[r] = acc;
}

// ---- attention: fused q/k/v norm+rope, flash partials; +1 cache-row writer block ----
__global__ __launch_bounds__(256) void attn_k(
    const float* __restrict__ qkvb,
    const float* __restrict__ gq, const float* __restrict__ gk,
    const float* __restrict__ cosT, const float* __restrict__ sinT,
    float* __restrict__ Kl, float* __restrict__ Vl,
    float* __restrict__ pm, float* __restrict__ pl, float* __restrict__ po){
  int b = blockIdx.x, tid = threadIdx.x, lane = tid & 63, wv = tid >> 6;

  if(b == NKV*NCH){ // cache-row writer: wave -> (kv, k|v)
    int kvv = wv >> 1, isV = wv & 1;
    const float* raw = qkvb + (isV ? 2560 : 2048) + kvv*HD;
    float4 o = normRope(raw, lane, isV ? nullptr : gk, cosT, sinT, !isV);
    float* dst = (isV ? Vl : Kl) + ((size_t)kvv*KVL + POS)*HD;
    ((float4*)dst)[lane] = o;
    return;
  }

  int kv = b & 1, c = b >> 1;          // c: 0..127
  __shared__ float q_s[4][HD];
  __shared__ float vf_s[HD];
  __shared__ float s_s[4][CP];
  __shared__ float s_w[4][CP];
  bool fresh = (c == NCH-1);

  { // q norm+rope: wave wv -> head kv*4+wv
    float4 o = normRope(qkvb + (kv*4 + wv)*HD, lane, gq, cosT, sinT, true);
    ((float4*)q_s[wv])[lane] = o;
  }
  float4 kf4 = {0,0,0,0};
  if(fresh){
    if(wv == 3) kf4 = normRope(qkvb + 2048 + kv*HD, lane, gk, cosT, sinT, true);
    if(wv == 1){
      float4 o = normRope(qkvb + 2560 + kv*HD, lane, nullptr, cosT, sinT, false);
      ((float4*)vf_s)[lane] = o;
    }
  }
  __syncthreads();

  float4 q4[4];
#pragma unroll
  for(int hh=0;hh<4;hh++) q4[hh] = ((const float4*)q_s[hh])[lane];
  const float4* Kp = (const float4*)(Kl + ((size_t)kv*KVL + c*CP)*HD);
#pragma unroll
  for(int j=0;j<4;j++){
    int p = wv*4 + j;
    float4 k4 = (fresh && p==CP-1) ? kf4 : Kp[(size_t)p*64 + lane];
    float d0 = dot4(k4,q4[0]), d1 = dot4(k4,q4[1]);
    float d2 = dot4(k4,q4[2]), d3 = dot4(k4,q4[3]);
    d0 = waveAllSum(d0); d1 = waveAllSum(d1);
    d2 = waveAllSum(d2); d3 = waveAllSum(d3);
    if(lane==0){ s_s[0][p]=d0; s_s[1][p]=d1; s_s[2][p]=d2; s_s[3][p]=d3; }
  }
  __syncthreads();

  if(tid < 64){ // per-head softmax over 16 positions (16-lane groups)
    int hh = tid >> 4, pp = tid & 15;
    float s = s_s[hh][pp];
    float m = s;
#pragma unroll
    for(int o=1;o<16;o<<=1) m = fmaxf(m, __shfl_xor(m,o,64));
    float e = __expf(s - m);
    float ls = e;
#pragma unroll
    for(int o=1;o<16;o<<=1) ls += __shfl_xor(ls,o,64);
    s_w[hh][pp] = e;
    if(pp==0){ int hg = kv*4 + hh; pm[hg*NCH + c] = m; pl[hg*NCH + c] = ls; }
  }
  __syncthreads();

  int d = tid;
  const float* Vp = Vl + ((size_t)kv*KVL + c*CP)*HD;
  float vv[CP];
#pragma unroll
  for(int p2=0;p2<CP;p2++) vv[p2] = Vp[(size_t)p2*HD + d];
  if(fresh) vv[CP-1] = vf_s[d];
  float acc[4] = {0.f,0.f,0.f,0.f};
#pragma unroll
  for(int p2=0;p2<CP;p2++){
#pragma unroll
    for(int hh=0;hh<4;hh++) acc[hh] += s_w[hh][p2]*vv[p2];
  }
#pragma unroll
  for(int hh=0;hh<4;hh++)
    po[((size_t)(kv*4+hh)*NCH + c)*HD + d] = acc[hh];
}

// ---- combine chunk partials -> ao ----
__global__ __launch_bounds__(256) void attn_c(const float* __restrict__ pm,
    const float* __restrict__ pl, const float* __restrict__ po, float* __restrict__ ao){
  int h = blockIdx.x, tid = threadIdx.x;
  __shared__ float sm[NCH], sl[NCH], se[NCH];
  if(tid < NCH){ sm[tid] = pm[h*NCH+tid]; sl[tid] = pl[h*NCH+tid]; }
  __syncthreads();
  float M = -1e30f;
  for(int c=0;c<NCH;c++) M = fmaxf(M, sm[c]);
  if(tid < NCH) se[tid] = __expf(sm[tid]-M);
  __syncthreads();
  float Lh = 0.f;
  for(int c=0;c<NCH;c++) Lh += sl[c]*se[c];
  float a0=0.f, a1=0.f, a2=0.f, a3=0.f;
#pragma unroll 1
  for(int c=0;c<NCH;c+=4){
    a0 += po[((size_t)h*NCH + c  )*HD + tid]*se[c];
    a1 += po[((size_t)h*NCH + c+1)*HD + tid]*se[c+1];
    a2 += po[((size_t)h*NCH + c+2)*HD + tid]*se[c+2];
    a3 += po[((size_t)h*NCH + c+3)*HD + tid]*se[c+3];
  }
  ao[h*HD + tid] = (a0+a1+a2+a3) / Lh;
}

// ---- generic GEMV: y[r] = W[r,:] . x  (batched loads) ----
template<int C>
__global__ __launch_bounds__(256) void gemv_k(const float* __restrict__ W,
    const float* __restrict__ x, float* __restrict__ y){
  __shared__ float xs[C];
  for(int i=threadIdx.x; i<C/4; i+=256)
    ((float4*)xs)[i] = ((const float4*)x)[i];
  __syncthreads();
  int lane = threadIdx.x & 63, wv = threadIdx.x >> 6;
  int r = blockIdx.x*4 + wv;
  const float4* Wr = (const float4*)(W + (size_t)r*C);
  const float4* xs4 = (const float4*)xs;
  float acc = 0.f;
#pragma unroll
  for(int ii=0;ii<C/2048;ii++){
    float4 w8[8];
#pragma unroll
    for(int i=0;i<8 && ii*8+i < C/256;i++) w8[i] = Wr[(ii*8+i)*64+lane];
#pragma unroll
    for(int i=0;i<8 && ii*8+i < C/256;i++) acc += dot4(w8[i], xs4[(ii*8+i)*64+lane]);
  }
  if(C < 2048){
    float4 w1 = Wr[lane];
    acc = dot4(w1, xs4[lane]);
  }
  acc = waveAllSum(acc);
  if(lane==0) y[r] = acc;
}

// ---- gate/up GEMV with fused post_attn prologue (batched 16 loads) ----
__global__ __launch_bounds__(256) void gateup_k(const float* __restrict__ Wg,
    const float* __restrict__ Wu, const float* __restrict__ y,
    const float* __restrict__ hA, const float* __restrict__ g_pa,
    const float* __restrict__ g_pf, float* __restrict__ hB, float* __restrict__ t){
  __shared__ float xs[DIM];
  __shared__ float red[4];
  int tid = threadIdx.x;
  float yv[8]; float ss1 = 0.f;
#pragma unroll
  for(int i=0;i<8;i++){ yv[i] = y[tid + i*256]; ss1 += yv[i]*yv[i]; }
  ss1 = blockSum256(ss1, red);
  float r1 = rsqrtf(ss1*(1.f/DIM) + 1e-6f);
  float hv[8]; float ss2 = 0.f;
#pragma unroll
  for(int i=0;i<8;i++){
    int idx = tid + i*256;
    hv[i] = hA[idx] + yv[i]*r1*g_pa[idx];
    ss2 += hv[i]*hv[i];
  }
  ss2 = blockSum256(ss2, red);
  float r2 = rsqrtf(ss2*(1.f/DIM) + 1e-6f);
#pragma unroll
  for(int i=0;i<8;i++){
    int idx = tid + i*256;
    xs[idx] = hv[i]*r2*g_pf[idx];
    if(blockIdx.x==0) hB[idx] = hv[i];
  }
  __syncthreads();
  int lane = tid & 63, wv = tid >> 6;
  int j = blockIdx.x*4 + wv;
  const float4* Gr = (const float4*)(Wg + (size_t)j*DIM);
  const float4* Ur = (const float4*)(Wu + (size_t)j*DIM);
  const float4* xs4 = (const float4*)xs;
  float4 g8[8], u8[8];
#pragma unroll
  for(int i=0;i<8;i++) g8[i] = Gr[i*64+lane];
#pragma unroll
  for(int i=0;i<8;i++) u8[i] = Ur[i*64+lane];
  float ag = 0.f, au = 0.f;
#pragma unroll
  for(int i=0;i<8;i++){
    float4 bv = xs4[i*64+lane];
    ag += dot4(g8[i], bv);
    au += dot4(u8[i], bv);
  }
  ag = waveAllSum(ag);
  au = waveAllSum(au);
  if(lane==0) t[j] = gelu_tanh(ag)*au;
}

// ---- down GEMV: 1 row per block, 4-wave column split, t read from L2 ----
__global__ __launch_bounds__(256) void down_k(const float* __restrict__ Wd,
    const float* __restrict__ t, float* __restrict__ mv){
  __shared__ float red[4];
  int tid = threadIdx.x, lane = tid & 63, wv = tid >> 6;
  int r = blockIdx.x;
  const float4* Wr = (const float4*)(Wd + (size_t)r*FFI) + wv*512;
  const float4* tp = (const float4*)t + wv*512;
  float4 w8[8], t8[8];
#pragma unroll
  for(int i=0;i<8;i++) w8[i] = Wr[i*64+lane];
#pragma unroll
  for(int i=0;i<8;i++) t8[i] = tp[i*64+lane];
  float acc = 0.f;
#pragma unroll
  for(int i=0;i<8;i++) acc += dot4(w8[i], t8[i]);
  acc = waveAllSum(acc);
  if(lane==0) red[wv] = acc;
  __syncthreads();
  if(tid==0) mv[r] = red[0]+red[1]+red[2]+red[3];
}

// ---- plg GEMV with fused post_ff prologue ----
__global__ __launch_bounds__(256) void plg_k(const float* __restrict__ W,
    const float* __restrict__ mv, const float* __restrict__ hB,
    const float* __restrict__ g_ff, const float* __restrict__ pls,
    float* __restrict__ hCout, float* __restrict__ gb){
  __shared__ float xs[DIM];
  __shared__ float red[4];
  int tid = threadIdx.x;
  float mvv[8]; float ss1 = 0.f;
#pragma unroll
  for(int i=0;i<8;i++){ mvv[i] = mv[tid + i*256]; ss1 += mvv[i]*mvv[i]; }
  ss1 = blockSum256(ss1, red);
  float r1 = rsqrtf(ss1*(1.f/DIM) + 1e-6f);
#pragma unroll
  for(int i=0;i<8;i++){
    int idx = tid + i*256;
    float hc = hB[idx] + mvv[i]*r1*g_ff[idx];
    xs[idx] = hc;
    if(blockIdx.x==0) hCout[idx] = hc;
  }
  __syncthreads();
  int lane = tid & 63, wv = tid >> 6;
  int r = blockIdx.x*4 + wv;
  const float4* Wr = (const float4*)(W + (size_t)r*DIM);
  const float4* xs4 = (const float4*)xs;
  float4 w8[8];
#pragma unroll
  for(int i=0;i<8;i++) w8[i] = Wr[i*64+lane];
  float acc = 0.f;
#pragma unroll
  for(int i=0;i<8;i++) acc += dot4(w8[i], xs4[i*64+lane]);
  acc = waveAllSum(acc);
  if(lane==0) gb[r] = gelu_tanh(acc)*pls[r];
}

// ---- final: out = (hC + rms(u)*g_pl)*ls ----
__global__ __launch_bounds__(256) void final_k(const float* __restrict__ u,
    const float* __restrict__ hC, const float* __restrict__ g_pl,
    const float* __restrict__ lsc, float* __restrict__ out){
  __shared__ float red[4];
  int tid = threadIdx.x;
  float uv[8]; float ss1 = 0.f;
#pragma unroll
  for(int i=0;i<8;i++){ uv[i] = u[tid + i*256]; ss1 += uv[i]*uv[i]; }
  ss1 = blockSum256(ss1, red);
  float r1 = rsqrtf(ss1*(1.f/DIM) + 1e-6f);
  float ls = lsc[0];
#pragma unroll
  for(int i=0;i<8;i++){
    int idx = tid + i*256;
    out[idx] = (hC[idx] + uv[i]*r1*g_pl[idx])*ls;
  }
}

extern "C" void kernel_launch(void* const* d_in, const int* in_sizes, int n_in,
                              void* d_out, int out_size, void* d_ws, size_t ws_size,
                              hipStream_t stream){
  const float* hidden   = (const float*)d_in[0];
  const float* plc      = (const float*)d_in[3];
  const float* cos_s    = (const float*)d_in[4];
  const float* sin_s    = (const float*)d_in[5];
  const float* cos_f    = (const float*)d_in[6];
  const float* sin_f    = (const float*)d_in[7];
  const float* K_in     = (const float*)d_in[8];
  const float* V_in     = (const float*)d_in[9];
  const float* w_q      = (const float*)d_in[10];
  const float* w_k      = (const float*)d_in[11];
  const float* w_v      = (const float*)d_in[12];
  const float* w_o      = (const float*)d_in[13];
  const float* g_in_ln  = (const float*)d_in[14];
  const float* g_q_norm = (const float*)d_in[15];
  const float* g_k_norm = (const float*)d_in[16];
  const float* g_pa_ln  = (const float*)d_in[17];
  const float* g_pf_ln  = (const float*)d_in[18];
  const float* g_ff_ln  = (const float*)d_in[19];
  const float* w_gate   = (const float*)d_in[20];
  const float* w_up     = (const float*)d_in[21];
  const float* w_down   = (const float*)d_in[22];
  const float* w_plg    = (const float*)d_in[23];
  const float* w_plp    = (const float*)d_in[24];
  const float* g_pl_ln  = (const float*)d_in[25];
  const float* l_scal   = (const float*)d_in[26];

  float* out  = (float*)d_out;
  float* outK = out + DIM;
  float* outV = outK + (size_t)NL*NKV*KVL*HD;

  float* ws   = (float*)d_ws;
  float* hA   = ws;
  float* hB   = ws + 2048;
  float* hC   = ws + 4096;
  float* qkvb = ws + 6144;    // 3072
  float* y    = ws + 9216;    // 2048
  float* t    = ws + 11264;   // 8192
  float* mv   = ws + 19456;   // 2048
  float* gb   = ws + 21504;   // 256
  float* u    = ws + 21760;   // 2048
  float* pm   = ws + 23808;   // 1024
  float* pl   = ws + 24832;   // 1024
  float* po   = ws + 25856;   // 8*128*256 = 262144
  float* ao   = ws + 288000;  // 2048

  (void)hipMemcpyAsync(outK, K_in, (size_t)NL*NKV*KVL*HD*sizeof(float),
                       hipMemcpyDeviceToDevice, stream);
  (void)hipMemcpyAsync(outV, V_in, (size_t)NL*NKV*KVL*HD*sizeof(float),
                       hipMemcpyDeviceToDevice, stream);

  for(int l=0;l<NL;l++){
    const float* cosT = (l==4) ? cos_f : cos_s;
    const float* sinT = (l==4) ? sin_f : sin_s;
    float* Kl = outK + (size_t)l*NKV*KVL*HD;
    float* Vl = outV + (size_t)l*NKV*KVL*HD;

    qkv_k<<<768,256,0,stream>>>(
        w_q + (size_t)l*NH*HD*DIM, w_k + (size_t)l*NKV*HD*DIM,
        w_v + (size_t)l*NKV*HD*DIM,
        hC, u,
        (l>0) ? g_pl_ln + (size_t)(l-1)*DIM : g_pl_ln,
        (l>0) ? l_scal + (l-1) : l_scal,
        g_in_ln + (size_t)l*DIM,
        (l==0) ? hidden : nullptr,
        hA, qkvb);

    attn_k<<<NKV*NCH+1,256,0,stream>>>(qkvb, g_q_norm + l*HD, g_k_norm + l*HD,
                                       cosT, sinT, Kl, Vl, pm, pl, po);

    attn_c<<<NH,256,0,stream>>>(pm, pl, po, ao);

    gemv_k<DIM><<<512,256,0,stream>>>(w_o + (size_t)l*DIM*NH*HD, ao, y);

    gateup_k<<<FFI/4,256,0,stream>>>(w_gate + (size_t)l*FFI*DIM,
                                     w_up + (size_t)l*FFI*DIM,
                                     y, hA, g_pa_ln + (size_t)l*DIM,
                                     g_pf_ln + (size_t)l*DIM, hB, t);

    down_k<<<DIM,256,0,stream>>>(w_down + (size_t)l*DIM*FFI, t, mv);

    plg_k<<<PLD/4,256,0,stream>>>(w_plg + (size_t)l*PLD*DIM, mv, hB,
                                  g_ff_ln + (size_t)l*DIM, plc + l*PLD, hC, gb);

    gemv_k<PLD><<<512,256,0,stream>>>(w_plp + (size_t)l*DIM*PLD, gb, u);
  }

  final_k<<<1,256,0,stream>>>(u, hC, g_pl_ln + (size_t)(NL-1)*DIM,
                              l_scal + (NL-1), out);
}